// Round 1
// baseline (351.427 us; speedup 1.0000x reference)
//
#include <hip/hip_runtime.h>
#include <hip/hip_bf16.h>

typedef short short8 __attribute__((ext_vector_type(8)));
typedef unsigned short u16x8 __attribute__((ext_vector_type(8)));
typedef float floatx4 __attribute__((ext_vector_type(4)));

// sizes: b=8, n=64 -> BN=512 groups; r=256; d=512; rows = 131072
#define ROWS 131072
#define D 512
#define RREG 256
#define NGROUP 512
#define FBAR_ELEMS (NGROUP * D)   // 262144 floats, output 0

__device__ __forceinline__ unsigned short f2bf(float f) {
    unsigned int u = __float_as_uint(f);
    unsigned int r = (u + 0x7fffu + ((u >> 16) & 1u)) >> 16;
    return (unsigned short)r;
}

// ---------------- kernel 1: W1 fp32 -> bf16 ----------------
__global__ __launch_bounds__(256) void conv_w1(const float* __restrict__ W1,
                                               unsigned short* __restrict__ W1bf) {
    int i = (blockIdx.x * 256 + threadIdx.x) * 4;
    float4 v = *reinterpret_cast<const float4*>(W1 + i);
    ushort4 o;
    o.x = f2bf(v.x); o.y = f2bf(v.y); o.z = f2bf(v.z); o.w = f2bf(v.w);
    *reinterpret_cast<ushort4*>(W1bf + i) = o;
}

// ---------------- kernel 2: fused normalize + GEMM + tanh + score ----------------
// grid 2048 blocks x 256 threads; block handles 64 rows, full K=512, N looped in 8 chunks of 64.
__global__ __launch_bounds__(256, 1) void gemm_score(
    const float* __restrict__ x, const unsigned short* __restrict__ W1bf,
    const float* __restrict__ b1, const float* __restrict__ w2,
    float* __restrict__ inv_norm, float* __restrict__ scores) {

    __shared__ unsigned short A_lds[64 * 512];   // 64 KiB, swizzled
    __shared__ unsigned short B_lds[64 * 512];   // 64 KiB, swizzled

    const int t = threadIdx.x;
    const int lane = t & 63;
    const int w = t >> 6;               // wave 0..3
    const int colLane = lane & 15;
    const int hi = lane >> 4;
    const long long row0 = (long long)blockIdx.x * 64;

    // ---- phase 1: normalize 16 rows per wave, stage bf16 xn into LDS (swizzled) ----
    #pragma unroll
    for (int i = 0; i < 16; ++i) {
        int r = w * 16 + i;
        long long g = row0 + r;
        const float* xr = x + (size_t)g * D + lane * 8;
        float4 v0 = *reinterpret_cast<const float4*>(xr);
        float4 v1 = *reinterpret_cast<const float4*>(xr + 4);
        float ss = v0.x*v0.x + v0.y*v0.y + v0.z*v0.z + v0.w*v0.w
                 + v1.x*v1.x + v1.y*v1.y + v1.z*v1.z + v1.w*v1.w;
        #pragma unroll
        for (int m = 1; m < 64; m <<= 1) ss += __shfl_xor(ss, m, 64);
        float inv = 1.0f / fmaxf(sqrtf(ss), 1e-12f);
        if (lane == 0) inv_norm[g] = inv;
        float vv[8] = {v0.x, v0.y, v0.z, v0.w, v1.x, v1.y, v1.z, v1.w};
        u16x8 pk;
        #pragma unroll
        for (int j = 0; j < 8; ++j) pk[j] = f2bf(vv[j] * inv);
        int byte = r * 1024 + ((lane * 16) ^ ((r & 7) << 4));
        *reinterpret_cast<u16x8*>((char*)A_lds + byte) = pk;
    }

    float sp[4] = {0.f, 0.f, 0.f, 0.f};

    for (int nc = 0; nc < 8; ++nc) {
        // ---- stage B chunk: W1 rows [nc*64, nc*64+64), all K, swizzled ----
        #pragma unroll
        for (int i = 0; i < 16; ++i) {
            int c = i * 256 + t;
            int col = c >> 6;       // 0..63 (local output col)
            int k16 = c & 63;       // 16B chunk index along K
            const unsigned short* src = W1bf + ((size_t)(nc * 64 + col) << 9) + k16 * 8;
            u16x8 vv = *reinterpret_cast<const u16x8*>(src);
            int byte = col * 1024 + ((k16 * 16) ^ ((col & 7) << 4));
            *reinterpret_cast<u16x8*>((char*)B_lds + byte) = vv;
        }
        __syncthreads();

        floatx4 acc[4] = {floatx4{0,0,0,0}, floatx4{0,0,0,0}, floatx4{0,0,0,0}, floatx4{0,0,0,0}};
        #pragma unroll
        for (int kk = 0; kk < 16; ++kk) {
            int kbyte = kk * 64 + hi * 16;        // byte offset of this lane-group's 8 bf16
            int arow = w * 16 + colLane;
            short8 af = *reinterpret_cast<const short8*>(
                (char*)A_lds + arow * 1024 + (kbyte ^ ((arow & 7) << 4)));
            #pragma unroll
            for (int j = 0; j < 4; ++j) {
                int bcol = j * 16 + colLane;
                short8 bf = *reinterpret_cast<const short8*>(
                    (char*)B_lds + bcol * 1024 + (kbyte ^ ((bcol & 7) << 4)));
                acc[j] = __builtin_amdgcn_mfma_f32_16x16x32_bf16(af, bf, acc[j], 0, 0, 0);
            }
        }

        // ---- chunk epilogue: +b1, tanh, dot with w2 into per-row partials ----
        int cbase = nc * 64;
        #pragma unroll
        for (int j = 0; j < 4; ++j) {
            int col = cbase + j * 16 + colLane;
            float wv = w2[col];
            float bb = b1[col];
            #pragma unroll
            for (int i = 0; i < 4; ++i) {
                sp[i] += wv * tanhf(acc[j][i] + bb);
            }
        }
        __syncthreads();
    }

    // ---- reduce score partials across the 16 column-lanes ----
    #pragma unroll
    for (int i = 0; i < 4; ++i) {
        float v = sp[i];
        v += __shfl_xor(v, 1, 16);
        v += __shfl_xor(v, 2, 16);
        v += __shfl_xor(v, 4, 16);
        v += __shfl_xor(v, 8, 16);
        if (colLane == 0) scores[row0 + w * 16 + hi * 4 + i] = v;
    }
}

// ---------------- kernel 3: softmax over r + fp32 weighted pooling ----------------
__global__ __launch_bounds__(256) void softmax_pool(
    const float* __restrict__ x, const float* __restrict__ inv_norm,
    const float* __restrict__ scores, float* __restrict__ out) {

    __shared__ float sdata[256];
    __shared__ float wts[256];
    const int t = threadIdx.x;
    const int bn = blockIdx.x;   // 0..511

    float s = scores[bn * RREG + t];
    sdata[t] = s;
    __syncthreads();
    for (int off = 128; off > 0; off >>= 1) {
        if (t < off) sdata[t] = fmaxf(sdata[t], sdata[t + off]);
        __syncthreads();
    }
    float mx = sdata[0];
    __syncthreads();
    float e = expf(s - mx);
    sdata[t] = e;
    __syncthreads();
    for (int off = 128; off > 0; off >>= 1) {
        if (t < off) sdata[t] += sdata[t + off];
        __syncthreads();
    }
    float denom = sdata[0];
    float alpha = e / denom;
    out[FBAR_ELEMS + bn * RREG + t] = alpha;      // output 1: alphas
    wts[t] = alpha * inv_norm[bn * RREG + t];
    __syncthreads();

    float a0 = 0.f, a1 = 0.f;
    const float* xb = x + (size_t)bn * RREG * D + 2 * t;
    #pragma unroll 8
    for (int r = 0; r < RREG; ++r) {
        float2 v = *reinterpret_cast<const float2*>(xb + (size_t)r * D);
        float wr = wts[r];
        a0 += wr * v.x;
        a1 += wr * v.y;
    }
    out[bn * D + 2 * t]     = a0;                 // output 0: fbar
    out[bn * D + 2 * t + 1] = a1;
}

extern "C" void kernel_launch(void* const* d_in, const int* in_sizes, int n_in,
                              void* d_out, int out_size, void* d_ws, size_t ws_size,
                              hipStream_t stream) {
    const float* x  = (const float*)d_in[0];
    const float* W1 = (const float*)d_in[1];
    const float* b1 = (const float*)d_in[2];
    const float* w2 = (const float*)d_in[3];
    // b2 (d_in[4]) shifts all scores uniformly -> softmax-invariant -> unused.
    float* out = (float*)d_out;

    unsigned short* W1bf = (unsigned short*)d_ws;                       // 512 KiB
    float* inv_norm = (float*)((char*)d_ws + (512 * 512 * 2));          // 512 KiB
    float* scores   = (float*)((char*)d_ws + (512 * 512 * 2) + ROWS * 4); // 512 KiB

    conv_w1<<<256, 256, 0, stream>>>(W1, W1bf);
    gemm_score<<<ROWS / 64, 256, 0, stream>>>(x, W1bf, b1, w2, inv_norm, scores);
    softmax_pool<<<NGROUP, 256, 0, stream>>>(x, inv_norm, scores, out);
}

// Round 2
// 338.645 us; speedup vs baseline: 1.0377x; 1.0377x over previous
//
#include <hip/hip_runtime.h>
#include <hip/hip_bf16.h>

typedef short short8 __attribute__((ext_vector_type(8)));
typedef float floatx4 __attribute__((ext_vector_type(4)));

#define NGROUP 512
#define RREG 256
#define D 512
#define FBAR_ELEMS (NGROUP * D)   // 262144

__device__ __forceinline__ unsigned short f2bf(float f) {
    unsigned int u = __float_as_uint(f);
    unsigned int r = (u + 0x7fffu + ((u >> 16) & 1u)) >> 16;
    return (unsigned short)r;
}
__device__ __forceinline__ float bf2f(unsigned short h) {
    return __uint_as_float(((unsigned int)h) << 16);
}

// ---- kernel 1: W1 fp32 -> bf16, PRE-SWIZZLED chunk layout ----
// Chunk nc (64 cols x 512 k): desired LDS image byte L holds
// W1bf[col = nc*64 + L/1024][k16 = ((L%1024) ^ ((col&7)<<4))/16, elem (L%16)/2].
// We store that image linearly so global_load_lds (linear dest) reproduces it.
__global__ __launch_bounds__(256) void conv_w1(const float* __restrict__ W1,
                                               unsigned short* __restrict__ W1s) {
    int tid = blockIdx.x * 256 + threadIdx.x;   // 0..65535
    int G = tid * 8;                            // byte offset in 512 KiB
    int nc = G >> 16;
    int L = G & 65535;
    int col_local = L >> 10;
    int sw = L & 1023;
    int k16 = (sw ^ ((col_local & 7) << 4)) >> 4;
    int j0 = (sw & 15) >> 1;                    // 0 or 4
    int col = nc * 64 + col_local;
    const float* src = W1 + col * 512 + k16 * 8 + j0;
    float4 v = *reinterpret_cast<const float4*>(src);
    ushort4 o;
    o.x = f2bf(v.x); o.y = f2bf(v.y); o.z = f2bf(v.z); o.w = f2bf(v.w);
    *reinterpret_cast<ushort4*>((char*)W1s + G) = o;
}

// ---- kernel 2: fully fused per-group kernel ----
// 512 blocks (one per (b,n) group), 512 threads = 8 waves, 32 rows/wave.
// xn kept in registers as bf16 MFMA A-fragments; W1 chunks through LDS;
// block softmax; pooling from the register A-fragments.
__global__ __launch_bounds__(512, 2) void fused(
    const float* __restrict__ x, const unsigned short* __restrict__ W1s,
    const float* __restrict__ b1, const float* __restrict__ W2v,
    float* __restrict__ out) {

    __shared__ unsigned short B_lds[32768];   // 64 KiB, one W1 chunk (swizzled image)
    __shared__ float scores_s[RREG];
    __shared__ float alpha_s[RREG];

    const int t = threadIdx.x;
    const int lane = t & 63;
    const int w = t >> 6;          // wave 0..7
    const int cl = lane & 15;
    const int hi = lane >> 4;
    const int bid = blockIdx.x;
    const size_t row0 = (size_t)bid * RREG;

    // stage B chunk nc into LDS (linear dest; source is pre-swizzled)
    auto stage = [&](int nc) {
        const char* gb = (const char*)W1s + nc * 65536 + lane * 16;
        #pragma unroll
        for (int i = 0; i < 8; ++i) {
            int lofs = (w * 8 + i) << 10;     // wave-uniform LDS base, HW adds lane*16
            __builtin_amdgcn_global_load_lds(
                (const __attribute__((address_space(1))) void*)(gb + lofs),
                (__attribute__((address_space(3))) void*)((char*)B_lds + lofs),
                16, 0, 0);
        }
    };

    stage(0);   // in flight during the x-load phase

    // ---- load + normalize + pack A fragments (two 16-row tiles per wave) ----
    // Lane l owns row (l&15) of each tile; k-positions c*32 + hi*8 + j (A-frag layout).
    short8 a0[16], a1[16];
    {
        float4 v[16][2];
        #pragma unroll
        for (int m = 0; m < 2; ++m) {
            const float* xp = x + (row0 + w * 32 + m * 16 + cl) * D + hi * 8;
            #pragma unroll
            for (int c = 0; c < 16; ++c) {
                v[c][0] = *reinterpret_cast<const float4*>(xp + c * 32);
                v[c][1] = *reinterpret_cast<const float4*>(xp + c * 32 + 4);
            }
            float ss = 0.f;
            #pragma unroll
            for (int c = 0; c < 16; ++c) {
                float4 p = v[c][0], q = v[c][1];
                ss += p.x*p.x + p.y*p.y + p.z*p.z + p.w*p.w;
                ss += q.x*q.x + q.y*q.y + q.z*q.z + q.w*q.w;
            }
            // row r is held by lanes {r, r+16, r+32, r+48}: butterfly over hi bits
            ss += __shfl_xor(ss, 16, 64);
            ss += __shfl_xor(ss, 32, 64);
            float inv = 1.0f / fmaxf(sqrtf(ss), 1e-12f);
            #pragma unroll
            for (int c = 0; c < 16; ++c) {
                short8 s;
                s[0] = (short)f2bf(v[c][0].x * inv);
                s[1] = (short)f2bf(v[c][0].y * inv);
                s[2] = (short)f2bf(v[c][0].z * inv);
                s[3] = (short)f2bf(v[c][0].w * inv);
                s[4] = (short)f2bf(v[c][1].x * inv);
                s[5] = (short)f2bf(v[c][1].y * inv);
                s[6] = (short)f2bf(v[c][1].z * inv);
                s[7] = (short)f2bf(v[c][1].w * inv);
                if (m == 0) a0[c] = s; else a1[c] = s;
            }
        }
    }

    // ---- GEMM over 8 column-chunks of 64; epilogue folds tanh + w2-dot ----
    float sp[2][4] = {{0.f,0.f,0.f,0.f},{0.f,0.f,0.f,0.f}};

    for (int nc = 0; nc < 8; ++nc) {
        if (nc > 0) { __syncthreads(); stage(nc); }
        __syncthreads();   // B chunk landed (vmcnt drained by barrier)

        floatx4 acc[2][4];
        #pragma unroll
        for (int j = 0; j < 4; ++j) { acc[0][j] = floatx4{0,0,0,0}; acc[1][j] = floatx4{0,0,0,0}; }

        #pragma unroll
        for (int kk = 0; kk < 16; ++kk) {
            const int kb = kk * 64 + hi * 16;
            #pragma unroll
            for (int j = 0; j < 4; ++j) {
                const int bcol = j * 16 + cl;
                short8 bf = *reinterpret_cast<const short8*>(
                    (const char*)B_lds + bcol * 1024 + (kb ^ ((bcol & 7) << 4)));
                acc[0][j] = __builtin_amdgcn_mfma_f32_16x16x32_bf16(a0[kk], bf, acc[0][j], 0, 0, 0);
                acc[1][j] = __builtin_amdgcn_mfma_f32_16x16x32_bf16(a1[kk], bf, acc[1][j], 0, 0, 0);
            }
        }

        #pragma unroll
        for (int j = 0; j < 4; ++j) {
            int col = nc * 64 + j * 16 + cl;
            float wv = W2v[col];
            float bb = b1[col];
            #pragma unroll
            for (int i = 0; i < 4; ++i) {
                sp[0][i] += wv * tanhf(acc[0][j][i] + bb);
                sp[1][i] += wv * tanhf(acc[1][j][i] + bb);
            }
        }
    }

    // ---- reduce score partials over the 16 column-lanes; C/D row = hi*4+i ----
    #pragma unroll
    for (int m = 0; m < 2; ++m) {
        #pragma unroll
        for (int i = 0; i < 4; ++i) {
            float vv = sp[m][i];
            vv += __shfl_xor(vv, 1, 64);
            vv += __shfl_xor(vv, 2, 64);
            vv += __shfl_xor(vv, 4, 64);
            vv += __shfl_xor(vv, 8, 64);
            if (cl == 0) scores_s[w * 32 + m * 16 + hi * 4 + i] = vv;
        }
    }
    __syncthreads();

    // ---- block softmax over the 256 region scores (B_lds reused as scratch) ----
    float* F = (float*)B_lds;
    float e = 0.f, sc = 0.f;
    if (t < RREG) { sc = scores_s[t]; F[t] = sc; }
    __syncthreads();
    for (int off = 128; off > 0; off >>= 1) {
        if (t < off) F[t] = fmaxf(F[t], F[t + off]);
        __syncthreads();
    }
    float mx = F[0];
    __syncthreads();
    if (t < RREG) { e = expf(sc - mx); F[t] = e; }
    __syncthreads();
    for (int off = 128; off > 0; off >>= 1) {
        if (t < off) F[t] += F[t + off];
        __syncthreads();
    }
    float denom = F[0];
    __syncthreads();
    if (t < RREG) {
        float al = e / denom;
        alpha_s[t] = al;
        out[FBAR_ELEMS + (size_t)bid * RREG + t] = al;   // output 1: alphas
    }
    __syncthreads();

    // ---- pooling: fbar[d] = sum_r alpha_r * xn[r][d], from register A-frags ----
    float* wred = (float*)B_lds;    // [8 waves][512 d]
    {
        float al0 = alpha_s[w * 32 + cl];
        float al1 = alpha_s[w * 32 + 16 + cl];
        #pragma unroll
        for (int c = 0; c < 16; ++c) {
            #pragma unroll
            for (int j = 0; j < 8; ++j) {
                float vv = al0 * bf2f((unsigned short)a0[c][j])
                         + al1 * bf2f((unsigned short)a1[c][j]);
                // sum over the 16 lanes (16 rows) holding this d
                vv += __shfl_xor(vv, 1, 64);
                vv += __shfl_xor(vv, 2, 64);
                vv += __shfl_xor(vv, 4, 64);
                vv += __shfl_xor(vv, 8, 64);
                if (cl == 0) wred[w * 512 + c * 32 + hi * 8 + j] = vv;
            }
        }
    }
    __syncthreads();
    {
        float s = 0.f;
        #pragma unroll
        for (int q = 0; q < 8; ++q) s += wred[q * 512 + t];
        out[(size_t)bid * D + t] = s;                    // output 0: fbar
    }
}

extern "C" void kernel_launch(void* const* d_in, const int* in_sizes, int n_in,
                              void* d_out, int out_size, void* d_ws, size_t ws_size,
                              hipStream_t stream) {
    const float* x  = (const float*)d_in[0];
    const float* W1 = (const float*)d_in[1];
    const float* b1 = (const float*)d_in[2];
    const float* w2 = (const float*)d_in[3];
    // b2 (d_in[4]) shifts all scores uniformly -> softmax-invariant -> unused.
    float* out = (float*)d_out;

    unsigned short* W1s = (unsigned short*)d_ws;   // 512 KiB pre-swizzled bf16 W1

    conv_w1<<<256, 256, 0, stream>>>(W1, W1s);
    fused<<<NGROUP, 512, 0, stream>>>(x, W1s, b1, w2, out);
}